// Round 1
// baseline (2445.955 us; speedup 1.0000x reference)
//
#include <hip/hip_runtime.h>
#include <cmath>

// Problem constants (match reference)
#define HSZ 128   // hidden size
#define ISZ 28    // input size
#define TSZ 28    // timesteps
#define CSZ 10    // classes
#define BT  16    // batch rows per block
#define NTHREADS 256  // tx=32 (4 cols each), ty=8 (2 rows each)

__global__ __launch_bounds__(NTHREADS, 2)
void rnn_fused(const float* __restrict__ x,
               const float* __restrict__ W_ih0, const float* __restrict__ W_hh0,
               const float* __restrict__ b_ih0, const float* __restrict__ b_hh0,
               const float* __restrict__ W_ih1, const float* __restrict__ W_hh1,
               const float* __restrict__ b_ih1, const float* __restrict__ b_hh1,
               const float* __restrict__ fc_w, const float* __restrict__ fc_b,
               float* __restrict__ out)
{
    __shared__ float h0[BT][HSZ];        // layer-0 hidden state
    __shared__ float h1[BT][HSZ];        // layer-1 hidden state
    __shared__ float xs[BT][ISZ];        // staged x_t
    __shared__ float Wi0t[ISZ][HSZ];     // W_ih0 transposed: [i][c]

    const int tid = threadIdx.x;
    const int tx  = tid & 31;            // 0..31 -> 4 cols each
    const int ty  = tid >> 5;            // 0..7  -> 2 rows each
    const int c0  = tx * 4;
    const int r0  = ty * 2;
    const int b0  = blockIdx.x * BT;

    // Stage W_ih0 transposed into LDS (once)
    for (int idx = tid; idx < ISZ * HSZ; idx += NTHREADS) {
        int i = idx / HSZ, c = idx % HSZ;
        Wi0t[i][c] = W_ih0[c * ISZ + i];
    }
    // Zero initial hidden states
    for (int idx = tid; idx < BT * HSZ; idx += NTHREADS) {
        (&h0[0][0])[idx] = 0.0f;
        (&h1[0][0])[idx] = 0.0f;
    }
    // Per-thread fused biases
    float bias0[4], bias1[4];
#pragma unroll
    for (int j = 0; j < 4; ++j) {
        bias0[j] = b_ih0[c0 + j] + b_hh0[c0 + j];
        bias1[j] = b_ih1[c0 + j] + b_hh1[c0 + j];
    }
    __syncthreads();

    for (int t = 0; t < TSZ; ++t) {
        // ---- stage x_t (16 rows x 28 floats) ----
        for (int idx = tid; idx < BT * ISZ; idx += NTHREADS) {
            int r = idx / ISZ, i = idx % ISZ;
            xs[r][i] = x[(b0 + r) * (TSZ * ISZ) + t * ISZ + i];
        }
        __syncthreads();

        // ---- layer 0: acc = bias + x_t @ W_ih0^T + h0 @ W_hh0^T ----
        float acc[2][4];
#pragma unroll
        for (int rr = 0; rr < 2; ++rr)
#pragma unroll
            for (int j = 0; j < 4; ++j) acc[rr][j] = bias0[j];

        // input part (K = 28), weights from LDS
        for (int i = 0; i < ISZ; ++i) {
            float xv0 = xs[r0][i];
            float xv1 = xs[r0 + 1][i];
#pragma unroll
            for (int j = 0; j < 4; ++j) {
                float w = Wi0t[i][c0 + j];
                acc[0][j] += xv0 * w;
                acc[1][j] += xv1 * w;
            }
        }
        // recurrent part (K = 128), W rows from global (L1/L2-hot)
#pragma unroll 2
        for (int k = 0; k < HSZ; k += 4) {
            float4 hv0 = *(const float4*)&h0[r0][k];
            float4 hv1 = *(const float4*)&h0[r0 + 1][k];
#pragma unroll
            for (int j = 0; j < 4; ++j) {
                float4 w = *(const float4*)&W_hh0[(c0 + j) * HSZ + k];
                acc[0][j] += hv0.x * w.x + hv0.y * w.y + hv0.z * w.z + hv0.w * w.w;
                acc[1][j] += hv1.x * w.x + hv1.y * w.y + hv1.z * w.z + hv1.w * w.w;
            }
        }
        __syncthreads();   // all reads of old h0 done
#pragma unroll
        for (int rr = 0; rr < 2; ++rr) {
            float4 v = make_float4(tanhf(acc[rr][0]), tanhf(acc[rr][1]),
                                   tanhf(acc[rr][2]), tanhf(acc[rr][3]));
            *(float4*)&h0[r0 + rr][c0] = v;
        }
        __syncthreads();   // new h0 visible

        // ---- layer 1: acc = bias + h0_new @ W_ih1^T + h1 @ W_hh1^T ----
#pragma unroll
        for (int rr = 0; rr < 2; ++rr)
#pragma unroll
            for (int j = 0; j < 4; ++j) acc[rr][j] = bias1[j];

#pragma unroll 2
        for (int k = 0; k < HSZ; k += 4) {
            float4 hv0 = *(const float4*)&h0[r0][k];
            float4 hv1 = *(const float4*)&h0[r0 + 1][k];
#pragma unroll
            for (int j = 0; j < 4; ++j) {
                float4 w = *(const float4*)&W_ih1[(c0 + j) * HSZ + k];
                acc[0][j] += hv0.x * w.x + hv0.y * w.y + hv0.z * w.z + hv0.w * w.w;
                acc[1][j] += hv1.x * w.x + hv1.y * w.y + hv1.z * w.z + hv1.w * w.w;
            }
            float4 g0 = *(const float4*)&h1[r0][k];
            float4 g1 = *(const float4*)&h1[r0 + 1][k];
#pragma unroll
            for (int j = 0; j < 4; ++j) {
                float4 w = *(const float4*)&W_hh1[(c0 + j) * HSZ + k];
                acc[0][j] += g0.x * w.x + g0.y * w.y + g0.z * w.z + g0.w * w.w;
                acc[1][j] += g1.x * w.x + g1.y * w.y + g1.z * w.z + g1.w * w.w;
            }
        }
        __syncthreads();   // all reads of old h1 done
#pragma unroll
        for (int rr = 0; rr < 2; ++rr) {
            float4 v = make_float4(tanhf(acc[rr][0]), tanhf(acc[rr][1]),
                                   tanhf(acc[rr][2]), tanhf(acc[rr][3]));
            *(float4*)&h1[r0 + rr][c0] = v;
        }
        __syncthreads();   // new h1 visible
    }

    // ---- FC epilogue: out[b, cc] = fc_b[cc] + h1[b,:] . fc_w[cc,:] ----
    for (int idx = tid; idx < BT * CSZ; idx += NTHREADS) {
        int r = idx / CSZ, cc = idx % CSZ;
        float a = fc_b[cc];
        for (int k = 0; k < HSZ; k += 4) {
            float4 hv = *(const float4*)&h1[r][k];
            float4 w  = *(const float4*)&fc_w[cc * HSZ + k];
            a += hv.x * w.x + hv.y * w.y + hv.z * w.z + hv.w * w.w;
        }
        out[(b0 + r) * CSZ + cc] = a;
    }
}

extern "C" void kernel_launch(void* const* d_in, const int* in_sizes, int n_in,
                              void* d_out, int out_size, void* d_ws, size_t ws_size,
                              hipStream_t stream) {
    const float* x     = (const float*)d_in[0];
    const float* W_ih0 = (const float*)d_in[1];
    const float* W_hh0 = (const float*)d_in[2];
    const float* b_ih0 = (const float*)d_in[3];
    const float* b_hh0 = (const float*)d_in[4];
    const float* W_ih1 = (const float*)d_in[5];
    const float* W_hh1 = (const float*)d_in[6];
    const float* b_ih1 = (const float*)d_in[7];
    const float* b_hh1 = (const float*)d_in[8];
    const float* fc_w  = (const float*)d_in[9];
    const float* fc_b  = (const float*)d_in[10];
    float* out = (float*)d_out;

    const int B = 8192;
    dim3 grid(B / BT), block(NTHREADS);
    rnn_fused<<<grid, block, 0, stream>>>(x, W_ih0, W_hh0, b_ih0, b_hh0,
                                          W_ih1, W_hh1, b_ih1, b_hh1,
                                          fc_w, fc_b, out);
}

// Round 2
// 147.972 us; speedup vs baseline: 16.5299x; 16.5299x over previous
//
#include <hip/hip_runtime.h>
#include <cmath>

#define HSZ 128
#define ISZ 28
#define TSZ 28
#define CSZ 10
#define BT  16     // batch rows per block
#define NT  256    // 4 waves
#define HP  136    // h row stride in halves (128 + 8 pad, keeps 16B alignment)

typedef _Float16 half_t;
typedef _Float16 v8h __attribute__((ext_vector_type(8)));
typedef float v4f __attribute__((ext_vector_type(4)));

__device__ __forceinline__ float fast_tanh(float x) {
    x = fminf(fmaxf(x, -15.f), 15.f);
    float e = __expf(2.f * x);
    return (e - 1.f) * __builtin_amdgcn_rcpf(e + 1.f);
}

// MFMA 16x16x32 f16 layouts (per guide, HW-verified):
//   A-frag: lane holds A[m = lane&15][k = (lane>>4)*8 + j], j=0..7
//   B-frag: lane holds B[k = (lane>>4)*8 + j][n = lane&15]  (B[k][n] = W[n][k])
//   C/D   : lane holds C[row = (lane>>4)*4 + r][col = lane&15], r=0..3
__global__ __launch_bounds__(NT, 2)
void rnn_mfma(const float* __restrict__ x,
              const float* __restrict__ W_ih0, const float* __restrict__ W_hh0,
              const float* __restrict__ b_ih0, const float* __restrict__ b_hh0,
              const float* __restrict__ W_ih1, const float* __restrict__ W_hh1,
              const float* __restrict__ b_ih1, const float* __restrict__ b_hh1,
              const float* __restrict__ fc_w, const float* __restrict__ fc_b,
              float* __restrict__ out)
{
    __shared__ half_t h0s[2][BT][HP];   // layer-0 hidden, ping-pong
    __shared__ half_t h1s[2][BT][HP];   // layer-1 hidden, ping-pong
    __shared__ half_t xss[2][BT][32];   // x_t staged (K padded 28->32)

    const int tid  = threadIdx.x;
    const int wave = tid >> 6;          // 0..3, owns cols [wave*32, wave*32+32)
    const int lane = tid & 63;
    const int ln   = lane & 15;
    const int quad = lane >> 4;
    const int kq   = quad * 8;
    const int b0   = blockIdx.x * BT;

    // ---- persistent weight B-fragments in registers (loaded once) ----
    v8h bWx[2];          // W_ih0 (K=32, zero-padded past 28)
    v8h bW0[2][4];       // W_hh0, 4 K-steps
    v8h bW1i[2][4];      // W_ih1
    v8h bW1h[2][4];      // W_hh1
    float bias0v[2], bias1v[2];

#pragma unroll
    for (int nj = 0; nj < 2; ++nj) {
        const int c = (wave * 2 + nj) * 16 + ln;   // output column this frag serves
        bias0v[nj] = b_ih0[c] + b_hh0[c];
        bias1v[nj] = b_ih1[c] + b_hh1[c];
#pragma unroll
        for (int j = 0; j < 8; ++j) {
            const int k = kq + j;
            bWx[nj][j] = (half_t)(k < ISZ ? W_ih0[c * ISZ + k] : 0.f);
        }
#pragma unroll
        for (int ks = 0; ks < 4; ++ks) {
            const float* p0 = W_hh0 + c * HSZ + ks * 32 + kq;
            const float* p1 = W_ih1 + c * HSZ + ks * 32 + kq;
            const float* p2 = W_hh1 + c * HSZ + ks * 32 + kq;
#pragma unroll
            for (int j = 0; j < 8; ++j) {
                bW0[nj][ks][j]  = (half_t)p0[j];
                bW1i[nj][ks][j] = (half_t)p1[j];
                bW1h[nj][ks][j] = (half_t)p2[j];
            }
        }
    }

    // ---- zero initial h (buffer 0), stage x_0 ----
    for (int idx = tid; idx < BT * HP; idx += NT) {
        (&h0s[0][0][0])[idx] = (half_t)0.f;
        (&h1s[0][0][0])[idx] = (half_t)0.f;
    }
    for (int idx = tid; idx < BT * 32; idx += NT) {
        const int m = idx >> 5, i = idx & 31;
        xss[0][m][i] = (half_t)(i < ISZ ? x[(size_t)(b0 + m) * (TSZ * ISZ) + i] : 0.f);
    }
    __syncthreads();

    int cA = 0, cB = 0;
    for (int t = 0; t < TSZ; ++t) {
        const int tb = t & 1;

        // stage x_{t+1} into the other buffer (visibility via barrier B1)
        if (t + 1 < TSZ) {
            for (int idx = tid; idx < BT * 32; idx += NT) {
                const int m = idx >> 5, i = idx & 31;
                xss[tb ^ 1][m][i] =
                    (half_t)(i < ISZ ? x[(size_t)(b0 + m) * (TSZ * ISZ) + (t + 1) * ISZ + i]
                                     : 0.f);
            }
        }

        // ---- layer 0: h0' = tanh(x_t Wi0^T + h0 Whh0^T + b) ----
        v4f acc[2];
#pragma unroll
        for (int nj = 0; nj < 2; ++nj)
            acc[nj] = (v4f){bias0v[nj], bias0v[nj], bias0v[nj], bias0v[nj]};
        {
            const v8h ax = *(const v8h*)&xss[tb][ln][kq];
#pragma unroll
            for (int nj = 0; nj < 2; ++nj)
                acc[nj] = __builtin_amdgcn_mfma_f32_16x16x32_f16(ax, bWx[nj], acc[nj], 0, 0, 0);
        }
#pragma unroll
        for (int ks = 0; ks < 4; ++ks) {
            const v8h ah = *(const v8h*)&h0s[cA][ln][ks * 32 + kq];
#pragma unroll
            for (int nj = 0; nj < 2; ++nj)
                acc[nj] = __builtin_amdgcn_mfma_f32_16x16x32_f16(ah, bW0[nj][ks], acc[nj], 0, 0, 0);
        }
#pragma unroll
        for (int nj = 0; nj < 2; ++nj) {
            const int c = (wave * 2 + nj) * 16 + ln;
#pragma unroll
            for (int r = 0; r < 4; ++r)
                h0s[cA ^ 1][quad * 4 + r][c] = (half_t)fast_tanh(acc[nj][r]);
        }
        __syncthreads();   // B1: h0' visible; x_{t+1} visible

        // ---- layer 1: h1' = tanh(h0' Wih1^T + h1 Whh1^T + b) ----
#pragma unroll
        for (int nj = 0; nj < 2; ++nj)
            acc[nj] = (v4f){bias1v[nj], bias1v[nj], bias1v[nj], bias1v[nj]};
#pragma unroll
        for (int ks = 0; ks < 4; ++ks) {
            const v8h a0 = *(const v8h*)&h0s[cA ^ 1][ln][ks * 32 + kq];
#pragma unroll
            for (int nj = 0; nj < 2; ++nj)
                acc[nj] = __builtin_amdgcn_mfma_f32_16x16x32_f16(a0, bW1i[nj][ks], acc[nj], 0, 0, 0);
            const v8h a1 = *(const v8h*)&h1s[cB][ln][ks * 32 + kq];
#pragma unroll
            for (int nj = 0; nj < 2; ++nj)
                acc[nj] = __builtin_amdgcn_mfma_f32_16x16x32_f16(a1, bW1h[nj][ks], acc[nj], 0, 0, 0);
        }
#pragma unroll
        for (int nj = 0; nj < 2; ++nj) {
            const int c = (wave * 2 + nj) * 16 + ln;
#pragma unroll
            for (int r = 0; r < 4; ++r)
                h1s[cB ^ 1][quad * 4 + r][c] = (half_t)fast_tanh(acc[nj][r]);
        }
        __syncthreads();   // B2: h1' visible
        cA ^= 1; cB ^= 1;
    }

    // ---- FC epilogue: out = h1_final @ fc_w^T + fc_b ----
    for (int idx = tid; idx < BT * CSZ; idx += NT) {
        const int m = idx / CSZ, cc = idx - m * CSZ;
        float s = fc_b[cc];
#pragma unroll 4
        for (int k = 0; k < HSZ; ++k)
            s += (float)h1s[cB][m][k] * fc_w[cc * HSZ + k];
        out[(b0 + m) * CSZ + cc] = s;
    }
}

extern "C" void kernel_launch(void* const* d_in, const int* in_sizes, int n_in,
                              void* d_out, int out_size, void* d_ws, size_t ws_size,
                              hipStream_t stream) {
    const float* x     = (const float*)d_in[0];
    const float* W_ih0 = (const float*)d_in[1];
    const float* W_hh0 = (const float*)d_in[2];
    const float* b_ih0 = (const float*)d_in[3];
    const float* b_hh0 = (const float*)d_in[4];
    const float* W_ih1 = (const float*)d_in[5];
    const float* W_hh1 = (const float*)d_in[6];
    const float* b_ih1 = (const float*)d_in[7];
    const float* b_hh1 = (const float*)d_in[8];
    const float* fc_w  = (const float*)d_in[9];
    const float* fc_b  = (const float*)d_in[10];
    float* out = (float*)d_out;

    const int B = in_sizes[0] / (TSZ * ISZ);   // 8192
    dim3 grid(B / BT), block(NT);
    rnn_mfma<<<grid, block, 0, stream>>>(x, W_ih0, W_hh0, b_ih0, b_hh0,
                                         W_ih1, W_hh1, b_ih1, b_hh1,
                                         fc_w, fc_b, out);
}

// Round 3
// 140.221 us; speedup vs baseline: 17.4436x; 1.0553x over previous
//
#include <hip/hip_runtime.h>

#define HSZ 128
#define ISZ 28
#define TSZ 28
#define CSZ 10
#define BT  16     // batch rows per block
#define NT  256    // 4 waves
#define HP  136    // h row stride in halves (uniform bank spread for b128/b64)
#define XP  40     // x row stride in halves

typedef _Float16 half_t;
typedef _Float16 v8h __attribute__((ext_vector_type(8)));
typedef _Float16 v4h __attribute__((ext_vector_type(4)));
typedef float v4f __attribute__((ext_vector_type(4)));

__device__ __forceinline__ float fast_tanh(float x) {
    // 1 - 2/(e^{2x}+1); saturates correctly for |x| large (inf -> 1 / -1)
    float e = __expf(2.f * x);
    return 1.f - 2.f * __builtin_amdgcn_rcpf(e + 1.f);
}

// MFMA 16x16x32 f16 layouts (HW-verified):
//   A-frag: lane holds A[m = lane&15][k = (lane>>4)*8 + j], j=0..7
//   B-frag: lane holds B[k = (lane>>4)*8 + j][n = lane&15]
//   C/D   : lane holds D[row = (lane>>4)*4 + r][col = lane&15], r=0..3
// We compute G = W · h^T  (A = weight tile, rows = hidden units; B = h^T,
// cols = batch). D rows = 4 consecutive hidden units, col = batch row ->
// h' write is one contiguous ds_write_b64 per tile.
__global__ __launch_bounds__(NT, 2)
void rnn_mfma2(const float* __restrict__ x,
               const float* __restrict__ W_ih0, const float* __restrict__ W_hh0,
               const float* __restrict__ b_ih0, const float* __restrict__ b_hh0,
               const float* __restrict__ W_ih1, const float* __restrict__ W_hh1,
               const float* __restrict__ b_ih1, const float* __restrict__ b_hh1,
               const float* __restrict__ fc_w, const float* __restrict__ fc_b,
               float* __restrict__ out)
{
    __shared__ half_t h0s[2][BT * HP];
    __shared__ half_t h1s[2][BT * HP];
    __shared__ half_t xss[2][BT * XP];

    const int tid  = threadIdx.x;
    const int wave = tid >> 6;
    const int lane = tid & 63;
    const int ln   = lane & 15;
    const int quad = lane >> 4;
    const int kq   = quad * 8;
    const int b0   = blockIdx.x * BT;

    // ---- persistent weight A-fragments (loaded once) ----
    // A row (hidden unit) this lane serves per tile:
    v8h aWx[2];          // W_ih0 (K padded 28->32)
    v8h aW0[2][4];       // W_hh0
    v8h aW1i[2][4];      // W_ih1
    v8h aW1h[2][4];      // W_hh1
    v4f bias0[2], bias1[2];

#pragma unroll
    for (int nt = 0; nt < 2; ++nt) {
        const int base = (wave * 2 + nt) * 16;
        const int row  = base + ln;          // A-frag row (hidden unit)
#pragma unroll
        for (int r = 0; r < 4; ++r) {
            const int c = base + quad * 4 + r;   // C/D row (hidden unit)
            bias0[nt][r] = b_ih0[c] + b_hh0[c];
            bias1[nt][r] = b_ih1[c] + b_hh1[c];
        }
#pragma unroll
        for (int j = 0; j < 8; ++j) {
            const int k = kq + j;
            aWx[nt][j] = (half_t)(k < ISZ ? W_ih0[row * ISZ + k] : 0.f);
        }
#pragma unroll
        for (int ks = 0; ks < 4; ++ks) {
            const float4* p0 = (const float4*)(W_hh0 + row * HSZ + ks * 32 + kq);
            const float4* p1 = (const float4*)(W_ih1 + row * HSZ + ks * 32 + kq);
            const float4* p2 = (const float4*)(W_hh1 + row * HSZ + ks * 32 + kq);
            float4 a = p0[0], b = p0[1];
            aW0[nt][ks] = (v8h){(half_t)a.x, (half_t)a.y, (half_t)a.z, (half_t)a.w,
                                (half_t)b.x, (half_t)b.y, (half_t)b.z, (half_t)b.w};
            a = p1[0]; b = p1[1];
            aW1i[nt][ks] = (v8h){(half_t)a.x, (half_t)a.y, (half_t)a.z, (half_t)a.w,
                                 (half_t)b.x, (half_t)b.y, (half_t)b.z, (half_t)b.w};
            a = p2[0]; b = p2[1];
            aW1h[nt][ks] = (v8h){(half_t)a.x, (half_t)a.y, (half_t)a.z, (half_t)a.w,
                                 (half_t)b.x, (half_t)b.y, (half_t)b.z, (half_t)b.w};
        }
    }

    // ---- prologue: zero h1(-1) + x pads, stage x0, x1 ----
    for (int idx = tid; idx < BT * XP; idx += NT) {
        xss[0][idx] = (half_t)0.f;
        xss[1][idx] = (half_t)0.f;
    }
    for (int idx = tid; idx < BT * HP; idx += NT)
        h1s[0][idx] = (half_t)0.f;
    __syncthreads();
    for (int idx = tid; idx < BT * ISZ; idx += NT) {
        const int m = idx / ISZ, i = idx - m * ISZ;
        const float* xr = x + (size_t)(b0 + m) * (TSZ * ISZ);
        xss[0][m * XP + i] = (half_t)xr[i];
        xss[1][m * XP + i] = (half_t)(ISZ + i < 2 * ISZ ? xr[ISZ + i] : 0.f);
    }
    __syncthreads();

    // ---- h0(0) = tanh(W_ih0 x0^T + b0) -> h0s[0] ----
    {
        const v8h bx = *(const v8h*)&xss[0][ln * XP + kq];
        v4f a0[2] = {bias0[0], bias0[1]};
#pragma unroll
        for (int nt = 0; nt < 2; ++nt)
            a0[nt] = __builtin_amdgcn_mfma_f32_16x16x32_f16(aWx[nt], bx, a0[nt], 0, 0, 0);
#pragma unroll
        for (int nt = 0; nt < 2; ++nt) {
            const int base = (wave * 2 + nt) * 16;
            v4h p = {(half_t)fast_tanh(a0[nt][0]), (half_t)fast_tanh(a0[nt][1]),
                     (half_t)fast_tanh(a0[nt][2]), (half_t)fast_tanh(a0[nt][3])};
            *(v4h*)&h0s[0][ln * HP + base + quad * 4] = p;
        }
    }
    __syncthreads();

    // ---- main loop: segment t computes h1(t) AND h0(t+1), one barrier ----
    for (int t = 0; t < TSZ - 1; ++t) {
        const int pr = t & 1;   // h0(t) in h0s[pr], h1(t-1) in h1s[pr], x(t+1) in xss[pr^1]

        // stage x(t+2) into xss[pr] (its old contents, x(t), were consumed last segment)
        if (t < TSZ - 2) {
            for (int idx = tid; idx < BT * ISZ; idx += NT) {
                const int m = idx / ISZ, i = idx - m * ISZ;
                xss[pr][m * XP + i] =
                    (half_t)x[(size_t)(b0 + m) * (TSZ * ISZ) + (t + 2) * ISZ + i];
            }
        }

        // B-fragments
        v8h bh0[4], bh1[4];
#pragma unroll
        for (int ks = 0; ks < 4; ++ks) {
            bh0[ks] = *(const v8h*)&h0s[pr][ln * HP + ks * 32 + kq];
            bh1[ks] = *(const v8h*)&h1s[pr][ln * HP + ks * 32 + kq];
        }
        const v8h bx = *(const v8h*)&xss[pr ^ 1][ln * XP + kq];

        v4f a1[2] = {bias1[0], bias1[1]};
        v4f a0[2] = {bias0[0], bias0[1]};
#pragma unroll
        for (int nt = 0; nt < 2; ++nt)
            a0[nt] = __builtin_amdgcn_mfma_f32_16x16x32_f16(aWx[nt], bx, a0[nt], 0, 0, 0);
#pragma unroll
        for (int ks = 0; ks < 4; ++ks) {
#pragma unroll
            for (int nt = 0; nt < 2; ++nt) {
                a1[nt] = __builtin_amdgcn_mfma_f32_16x16x32_f16(aW1i[nt][ks], bh0[ks], a1[nt], 0, 0, 0);
                a1[nt] = __builtin_amdgcn_mfma_f32_16x16x32_f16(aW1h[nt][ks], bh1[ks], a1[nt], 0, 0, 0);
                a0[nt] = __builtin_amdgcn_mfma_f32_16x16x32_f16(aW0[nt][ks], bh0[ks], a0[nt], 0, 0, 0);
            }
        }

        // tanh + packed writes: h1(t) -> h1s[pr^1], h0(t+1) -> h0s[pr^1]
#pragma unroll
        for (int nt = 0; nt < 2; ++nt) {
            const int base = (wave * 2 + nt) * 16;
            v4h p1 = {(half_t)fast_tanh(a1[nt][0]), (half_t)fast_tanh(a1[nt][1]),
                      (half_t)fast_tanh(a1[nt][2]), (half_t)fast_tanh(a1[nt][3])};
            *(v4h*)&h1s[pr ^ 1][ln * HP + base + quad * 4] = p1;
            v4h p0 = {(half_t)fast_tanh(a0[nt][0]), (half_t)fast_tanh(a0[nt][1]),
                      (half_t)fast_tanh(a0[nt][2]), (half_t)fast_tanh(a0[nt][3])};
            *(v4h*)&h0s[pr ^ 1][ln * HP + base + quad * 4] = p0;
        }
        __syncthreads();
    }

    // ---- final segment: h1(27) only ----
    {
        const int pr = (TSZ - 1) & 1;   // = 1
        v8h bh0[4], bh1[4];
#pragma unroll
        for (int ks = 0; ks < 4; ++ks) {
            bh0[ks] = *(const v8h*)&h0s[pr][ln * HP + ks * 32 + kq];
            bh1[ks] = *(const v8h*)&h1s[pr][ln * HP + ks * 32 + kq];
        }
        v4f a1[2] = {bias1[0], bias1[1]};
#pragma unroll
        for (int ks = 0; ks < 4; ++ks) {
#pragma unroll
            for (int nt = 0; nt < 2; ++nt) {
                a1[nt] = __builtin_amdgcn_mfma_f32_16x16x32_f16(aW1i[nt][ks], bh0[ks], a1[nt], 0, 0, 0);
                a1[nt] = __builtin_amdgcn_mfma_f32_16x16x32_f16(aW1h[nt][ks], bh1[ks], a1[nt], 0, 0, 0);
            }
        }
#pragma unroll
        for (int nt = 0; nt < 2; ++nt) {
            const int base = (wave * 2 + nt) * 16;
            v4h p1 = {(half_t)fast_tanh(a1[nt][0]), (half_t)fast_tanh(a1[nt][1]),
                      (half_t)fast_tanh(a1[nt][2]), (half_t)fast_tanh(a1[nt][3])};
            *(v4h*)&h1s[pr ^ 1][ln * HP + base + quad * 4] = p1;
        }
        __syncthreads();
    }

    // ---- FC epilogue: out = h1(27) @ fc_w^T + fc_b  (h1(27) in h1s[0]) ----
    if (tid < BT * CSZ) {
        const int m = tid / CSZ, cc = tid - m * CSZ;
        float s = fc_b[cc];
#pragma unroll
        for (int k8 = 0; k8 < HSZ / 8; ++k8) {
            const v8h hv = *(const v8h*)&h1s[0][m * HP + k8 * 8];
            const float4 w0 = *(const float4*)(fc_w + cc * HSZ + k8 * 8);
            const float4 w1 = *(const float4*)(fc_w + cc * HSZ + k8 * 8 + 4);
            s += (float)hv[0] * w0.x + (float)hv[1] * w0.y +
                 (float)hv[2] * w0.z + (float)hv[3] * w0.w +
                 (float)hv[4] * w1.x + (float)hv[5] * w1.y +
                 (float)hv[6] * w1.z + (float)hv[7] * w1.w;
        }
        out[(b0 + m) * CSZ + cc] = s;
    }
}

extern "C" void kernel_launch(void* const* d_in, const int* in_sizes, int n_in,
                              void* d_out, int out_size, void* d_ws, size_t ws_size,
                              hipStream_t stream) {
    const float* x     = (const float*)d_in[0];
    const float* W_ih0 = (const float*)d_in[1];
    const float* W_hh0 = (const float*)d_in[2];
    const float* b_ih0 = (const float*)d_in[3];
    const float* b_hh0 = (const float*)d_in[4];
    const float* W_ih1 = (const float*)d_in[5];
    const float* W_hh1 = (const float*)d_in[6];
    const float* b_ih1 = (const float*)d_in[7];
    const float* b_hh1 = (const float*)d_in[8];
    const float* fc_w  = (const float*)d_in[9];
    const float* fc_b  = (const float*)d_in[10];
    float* out = (float*)d_out;

    const int B = in_sizes[0] / (TSZ * ISZ);   // 8192
    dim3 grid(B / BT), block(NT);
    rnn_mfma2<<<grid, block, 0, stream>>>(x, W_ih0, W_hh0, b_ih0, b_hh0,
                                          W_ih1, W_hh1, b_ih1, b_hh1,
                                          fc_w, fc_b, out);
}

// Round 4
// 127.290 us; speedup vs baseline: 19.2155x; 1.1016x over previous
//
#include <hip/hip_runtime.h>

#define HSZ 128
#define ISZ 28
#define TSZ 28
#define CSZ 10
#define BT  16     // batch rows per block
#define NT  512    // 8 waves, one 16-row hidden tile each
#define HP  136    // h row stride in halves
#define XP  32     // x row stride in halves (K padded 28->32)

typedef _Float16 half_t;
typedef _Float16 v8h __attribute__((ext_vector_type(8)));
typedef _Float16 v4h __attribute__((ext_vector_type(4)));
typedef float v4f __attribute__((ext_vector_type(4)));

__device__ __forceinline__ float fast_tanh(float x) {
    // 1 - 2/(e^{2x}+1); saturates correctly (+-inf -> +-1)
    float e = __expf(2.f * x);
    return 1.f - 2.f * __builtin_amdgcn_rcpf(e + 1.f);
}

// MFMA 16x16x32 f16 layouts (HW-verified):
//   A-frag: lane holds A[m = lane&15][k = (lane>>4)*8 + j], j=0..7
//   B-frag: lane holds B[k = (lane>>4)*8 + j][n = lane&15]
//   C/D   : lane holds D[row = (lane>>4)*4 + r][col = lane&15], r=0..3
// G = W · h^T: A = weight tile (rows = hidden units), B[k][n] = h[batch n][k].
// D rows = 4 consecutive hidden units at batch col ln -> one ds_write_b64.
__global__ __launch_bounds__(NT, 4)   // 4 waves/SIMD -> 2 blocks/CU, VGPR<=128
void rnn_mfma3(const float* __restrict__ x,
               const float* __restrict__ W_ih0, const float* __restrict__ W_hh0,
               const float* __restrict__ b_ih0, const float* __restrict__ b_hh0,
               const float* __restrict__ W_ih1, const float* __restrict__ W_hh1,
               const float* __restrict__ b_ih1, const float* __restrict__ b_hh1,
               const float* __restrict__ fc_w, const float* __restrict__ fc_b,
               float* __restrict__ out)
{
    __shared__ half_t h0s[2][BT * HP];
    __shared__ half_t h1s[2][BT * HP];
    __shared__ half_t xss[2][BT * XP];

    const int tid  = threadIdx.x;
    const int wave = tid >> 6;          // 0..7 -> row-tile [wave*16, wave*16+16)
    const int lane = tid & 63;
    const int ln   = lane & 15;
    const int quad = lane >> 4;
    const int kq   = quad * 8;
    const int b0   = blockIdx.x * BT;
    const int base = wave * 16;
    const int row  = base + ln;         // A-frag row (hidden unit)

    // ---- persistent weight A-fragments (loaded once): 13 frags = 52 VGPR ----
    v8h aWx, aW0[4], aW1i[4], aW1h[4];
    v4f bias0, bias1;
    {
        float4 p = *(const float4*)(b_ih0 + base + quad * 4);
        float4 q = *(const float4*)(b_hh0 + base + quad * 4);
        bias0 = (v4f){p.x + q.x, p.y + q.y, p.z + q.z, p.w + q.w};
        p = *(const float4*)(b_ih1 + base + quad * 4);
        q = *(const float4*)(b_hh1 + base + quad * 4);
        bias1 = (v4f){p.x + q.x, p.y + q.y, p.z + q.z, p.w + q.w};
    }
    {
        const float* pw = W_ih0 + row * ISZ + kq;      // kq<=24, kq+3<=27 in-row
        float4 a = *(const float4*)pw;
        float4 b = (kq < 24) ? *(const float4*)(pw + 4) : make_float4(0.f, 0.f, 0.f, 0.f);
        aWx = (v8h){(half_t)a.x, (half_t)a.y, (half_t)a.z, (half_t)a.w,
                    (half_t)b.x, (half_t)b.y, (half_t)b.z, (half_t)b.w};
    }
#pragma unroll
    for (int ks = 0; ks < 4; ++ks) {
        const float4* p0 = (const float4*)(W_hh0 + row * HSZ + ks * 32 + kq);
        const float4* p1 = (const float4*)(W_ih1 + row * HSZ + ks * 32 + kq);
        const float4* p2 = (const float4*)(W_hh1 + row * HSZ + ks * 32 + kq);
        float4 a = p0[0], b = p0[1];
        aW0[ks] = (v8h){(half_t)a.x, (half_t)a.y, (half_t)a.z, (half_t)a.w,
                        (half_t)b.x, (half_t)b.y, (half_t)b.z, (half_t)b.w};
        a = p1[0]; b = p1[1];
        aW1i[ks] = (v8h){(half_t)a.x, (half_t)a.y, (half_t)a.z, (half_t)a.w,
                         (half_t)b.x, (half_t)b.y, (half_t)b.z, (half_t)b.w};
        a = p2[0]; b = p2[1];
        aW1h[ks] = (v8h){(half_t)a.x, (half_t)a.y, (half_t)a.z, (half_t)a.w,
                         (half_t)b.x, (half_t)b.y, (half_t)b.z, (half_t)b.w};
    }

    // ---- x staging: thread <-> (batch row, input col), 512 = 16x32 exactly ----
    const int  xm  = tid >> 5;
    const int  xi  = tid & 31;
    const bool xok = xi < ISZ;
    const float* xrow = x + (size_t)(b0 + xm) * (TSZ * ISZ) + xi;

    // prologue: stage x0, x1 directly; x2 -> register pipeline
    xss[0][xm * XP + xi] = (half_t)(xok ? xrow[0] : 0.f);
    xss[1][xm * XP + xi] = (half_t)(xok ? xrow[ISZ] : 0.f);
    float xcur = xok ? xrow[2 * ISZ] : 0.f;     // holds x(t+2) at segment t

    for (int idx = tid; idx < BT * HP; idx += NT)
        h1s[0][idx] = (half_t)0.f;              // h1(-1) = 0
    __syncthreads();

    // ---- h0(0) = tanh(W_ih0 x0^T + b0) -> h0s[0] ----
    {
        const v8h bx = *(const v8h*)&xss[0][ln * XP + kq];
        v4f a0 = bias0;
        a0 = __builtin_amdgcn_mfma_f32_16x16x32_f16(aWx, bx, a0, 0, 0, 0);
        v4h p = {(half_t)fast_tanh(a0[0]), (half_t)fast_tanh(a0[1]),
                 (half_t)fast_tanh(a0[2]), (half_t)fast_tanh(a0[3])};
        *(v4h*)&h0s[0][ln * HP + base + quad * 4] = p;
    }
    __syncthreads();

    // ---- main loop: segment t computes h1(t) and h0(t+1) ----
    for (int t = 0; t < TSZ - 1; ++t) {
        const int pr = t & 1;   // h0(t)->h0s[pr], h1(t-1)->h1s[pr], x(t+1)->xss[pr^1]

        // issue prefetch of x(t+3) early (in flight across this whole segment)
        float xnew = 0.f;
        if (t < TSZ - 3 && xok) xnew = xrow[(t + 3) * ISZ];

        // B-fragments from LDS
        v8h bh0[4];
#pragma unroll
        for (int ks = 0; ks < 4; ++ks)
            bh0[ks] = *(const v8h*)&h0s[pr][ln * HP + ks * 32 + kq];
        const v8h bx = *(const v8h*)&xss[pr ^ 1][ln * XP + kq];

        v4f a1 = bias1, a0 = bias0;
        a0 = __builtin_amdgcn_mfma_f32_16x16x32_f16(aWx, bx, a0, 0, 0, 0);
#pragma unroll
        for (int ks = 0; ks < 4; ++ks) {
            const v8h bh1 = *(const v8h*)&h1s[pr][ln * HP + ks * 32 + kq];
            a1 = __builtin_amdgcn_mfma_f32_16x16x32_f16(aW1i[ks], bh0[ks], a1, 0, 0, 0);
            a1 = __builtin_amdgcn_mfma_f32_16x16x32_f16(aW1h[ks], bh1,     a1, 0, 0, 0);
            a0 = __builtin_amdgcn_mfma_f32_16x16x32_f16(aW0[ks],  bh0[ks], a0, 0, 0, 0);
        }

        // tanh + packed h writes
        {
            v4h p1 = {(half_t)fast_tanh(a1[0]), (half_t)fast_tanh(a1[1]),
                      (half_t)fast_tanh(a1[2]), (half_t)fast_tanh(a1[3])};
            *(v4h*)&h1s[pr ^ 1][ln * HP + base + quad * 4] = p1;
            v4h p0 = {(half_t)fast_tanh(a0[0]), (half_t)fast_tanh(a0[1]),
                      (half_t)fast_tanh(a0[2]), (half_t)fast_tanh(a0[3])};
            *(v4h*)&h0s[pr ^ 1][ln * HP + base + quad * 4] = p0;
        }

        // write x(t+2) (loaded a full segment ago) into the freed x buffer
        if (t < TSZ - 2)
            xss[pr][xm * XP + xi] = (half_t)xcur;
        xcur = xnew;

        __syncthreads();
    }

    // ---- final segment: h1(27) only -> h1s[0] ----
    {
        const int pr = (TSZ - 1) & 1;   // = 1
        v4f a1 = bias1;
#pragma unroll
        for (int ks = 0; ks < 4; ++ks) {
            const v8h bh0 = *(const v8h*)&h0s[pr][ln * HP + ks * 32 + kq];
            const v8h bh1 = *(const v8h*)&h1s[pr][ln * HP + ks * 32 + kq];
            a1 = __builtin_amdgcn_mfma_f32_16x16x32_f16(aW1i[ks], bh0, a1, 0, 0, 0);
            a1 = __builtin_amdgcn_mfma_f32_16x16x32_f16(aW1h[ks], bh1, a1, 0, 0, 0);
        }
        v4h p1 = {(half_t)fast_tanh(a1[0]), (half_t)fast_tanh(a1[1]),
                  (half_t)fast_tanh(a1[2]), (half_t)fast_tanh(a1[3])};
        *(v4h*)&h1s[pr ^ 1][ln * HP + base + quad * 4] = p1;
    }
    __syncthreads();

    // ---- FC epilogue: out = h1(27) @ fc_w^T + fc_b ----
    if (tid < BT * CSZ) {
        const int m = tid / CSZ, cc = tid - m * CSZ;
        float s = fc_b[cc];
#pragma unroll
        for (int k8 = 0; k8 < HSZ / 8; ++k8) {
            const v8h hv = *(const v8h*)&h1s[0][m * HP + k8 * 8];
            const float4 w0 = *(const float4*)(fc_w + cc * HSZ + k8 * 8);
            const float4 w1 = *(const float4*)(fc_w + cc * HSZ + k8 * 8 + 4);
            s += (float)hv[0] * w0.x + (float)hv[1] * w0.y +
                 (float)hv[2] * w0.z + (float)hv[3] * w0.w +
                 (float)hv[4] * w1.x + (float)hv[5] * w1.y +
                 (float)hv[6] * w1.z + (float)hv[7] * w1.w;
        }
        out[(b0 + m) * CSZ + cc] = s;
    }
}

extern "C" void kernel_launch(void* const* d_in, const int* in_sizes, int n_in,
                              void* d_out, int out_size, void* d_ws, size_t ws_size,
                              hipStream_t stream) {
    const float* x     = (const float*)d_in[0];
    const float* W_ih0 = (const float*)d_in[1];
    const float* W_hh0 = (const float*)d_in[2];
    const float* b_ih0 = (const float*)d_in[3];
    const float* b_hh0 = (const float*)d_in[4];
    const float* W_ih1 = (const float*)d_in[5];
    const float* W_hh1 = (const float*)d_in[6];
    const float* b_ih1 = (const float*)d_in[7];
    const float* b_hh1 = (const float*)d_in[8];
    const float* fc_w  = (const float*)d_in[9];
    const float* fc_b  = (const float*)d_in[10];
    float* out = (float*)d_out;

    const int B = in_sizes[0] / (TSZ * ISZ);   // 8192
    dim3 grid(B / BT), block(NT);
    rnn_mfma3<<<grid, block, 0, stream>>>(x, W_ih0, W_hh0, b_ih0, b_hh0,
                                          W_ih1, W_hh1, b_ih1, b_hh1,
                                          fc_w, fc_b, out);
}